// Round 9
// baseline (389.783 us; speedup 1.0000x reference)
//
#include <hip/hip_runtime.h>
#include <hip/hip_bf16.h>
#include <cstdint>

// ---------------------------------------------------------------------------
// LocalMultiHeadAttention: B=2, T=1024, D=1024, H=16, dh=64, band=65 (half 32)
// 2-dispatch persistent megakernel build (launch gaps ~5-6us each were ~28us
// of R8's 76us):
//   megaA (768 blocks, 3/CU guaranteed): prep (flat-decode) -> gbar -> QKV gemm
//   megaB (512 blocks, 2/CU guaranteed): attn -> gbar -> out-proj -> gbar -> LN
// Grid barriers: monotonic counter in d_ws (zeroed via hipMemsetAsync),
// release atomic add + acquire atomic load spin (agent scope; never plain
// reads -- per-XCD L2 staleness). Phase bodies are R8-verbatim.
// Ledger: BK=64 locked (R7: BK=128 regressed). QKV 768-tile balance kept (R8).
// Bisection rider: prep uses R4's quarantined flat-bid decode on purpose --
// fail@0.398 => flat-decode guilty; pass => exonerated.
// ---------------------------------------------------------------------------

typedef __bf16 bf16x8 __attribute__((ext_vector_type(8)));
typedef __bf16 bf16x4 __attribute__((ext_vector_type(4)));
typedef float f32x4 __attribute__((ext_vector_type(4)));

#define GLD_LDS(gptr, lptr)                                                    \
  __builtin_amdgcn_global_load_lds(                                            \
      (const __attribute__((address_space(1))) void*)(gptr),                   \
      (__attribute__((address_space(3))) void*)(lptr), 16, 0, 0)

// ---------------- device-scope grid barrier --------------------------------
__device__ __forceinline__ void grid_barrier(unsigned* cnt, unsigned target) {
  __syncthreads();
  if (threadIdx.x == 0) {
    __threadfence();  // release all prior global writes (agent scope)
    __hip_atomic_fetch_add(cnt, 1u, __ATOMIC_RELEASE, __HIP_MEMORY_SCOPE_AGENT);
    while (__hip_atomic_load(cnt, __ATOMIC_ACQUIRE, __HIP_MEMORY_SCOPE_AGENT) <
           target)
      __builtin_amdgcn_s_sleep(2);
    __threadfence();  // acquire side for the rest of the CU
  }
  __syncthreads();
}

// ---------------- megaA: prep + QKV projection -----------------------------
// 768 blocks = exactly 3/CU: LDS 41.2KB (<53.3K), launch_bounds(256,3)
// caps VGPR<=170. All blocks co-resident -> barrier safe.
__global__ __launch_bounds__(256, 3) void megaA(
    const float* __restrict__ x, const float* __restrict__ ctxin,
    const float* __restrict__ Wq, const float* __restrict__ Wk,
    const float* __restrict__ Wv, const float* __restrict__ Wo,
    __bf16* __restrict__ Xb, __bf16* __restrict__ Cb,
    __bf16* __restrict__ Wqkvt, __bf16* __restrict__ Wot,
    __bf16* __restrict__ QKVb, unsigned* bar) {
  __shared__ float tile[64][65];
  __shared__ alignas(16) __bf16 As[64 * 64];
  __shared__ alignas(16) __bf16 Bs[128 * 64];
  const int tid = threadIdx.x;
  const int bid = blockIdx.x;

  // ---- phase 0: prep, 1536 units over 768 blocks (2 each) ----
  for (int u = bid; u < 1536; u += 768) {
    if (u < 1024) {  // weight transpose tile (body == proven prep2 z<4)
      const int z = u >> 8;
      const float* W = z == 0 ? Wq : z == 1 ? Wk : z == 2 ? Wv : Wo;
      __bf16* Wt = (z == 3) ? Wot : Wqkvt + (size_t)z * 1024 * 1024;
      const int k0 = ((u >> 4) & 15) * 64, n0 = (u & 15) * 64;
      const int tx = tid & 63, ty = tid >> 6;
#pragma unroll
      for (int r = ty; r < 64; r += 4)
        tile[r][tx] = W[(size_t)(k0 + r) * 1024 + n0 + tx];
      __syncthreads();
#pragma unroll
      for (int r = ty; r < 64; r += 4)
        Wt[(size_t)(n0 + r) * 1024 + k0 + tx] = (__bf16)tile[tx][r];
    } else {  // cvt (body == proven prep2 z>=4)
      const int c = u - 1024;  // 0..511
      const float* in = (c < 256) ? x : ctxin;
      __bf16* outp = (c < 256) ? Xb : Cb;
      const int base = (c & 255) * 2048;
#pragma unroll
      for (int it = 0; it < 8; ++it) {
        const int i = base + it * 256 + tid;
        float4 v = ((const float4*)in)[i];
        bf16x4 o;
        o[0] = (__bf16)v.x; o[1] = (__bf16)v.y;
        o[2] = (__bf16)v.z; o[3] = (__bf16)v.w;
        ((bf16x4*)outp)[i] = o;
      }
    }
    __syncthreads();  // tile reuse fence between prep units
  }

  grid_barrier(bar, 768);

  // ---- phase 1: QKV gemm, tile = bid (24 n-tiles x 32 m-tiles) ----
  {
    const int m0 = (bid / 24) * 64, n0 = (bid % 24) * 128;
    const __bf16* A = (n0 < 1024) ? Xb : Cb;
    const int K = 1024, ldc = 3072;
    const int w = tid >> 6, lane = tid & 63;
    const int wr = w >> 1, wc = w & 1;
    const int lrow = lane & 15, lk = (lane >> 4) * 8;

    f32x4 acc[2][4] = {};

    for (int kt = 0; kt < K; kt += 64) {
      __syncthreads();
#pragma unroll
      for (int it = 0; it < 4; ++it) {
        const int c = it * 256 + tid;
        const int row = c >> 3;
        const int ko = (c & 7) * 8;
        if (row < 64)  // wave-uniform A guard (R6/R8-proven)
          GLD_LDS(A + (size_t)(m0 + row) * K + kt + ko, As + c * 8);
        GLD_LDS(Wqkvt + (size_t)(n0 + row) * K + kt + ko, Bs + c * 8);
      }
      __syncthreads();
#pragma unroll
      for (int ks = 0; ks < 64; ks += 32) {
        bf16x8 av[2], bv[4];
#pragma unroll
        for (int mi = 0; mi < 2; ++mi)
          av[mi] = *(const bf16x8*)&As[(wr * 32 + mi * 16 + lrow) * 64 + ks + lk];
#pragma unroll
        for (int ni = 0; ni < 4; ++ni)
          bv[ni] = *(const bf16x8*)&Bs[(wc * 64 + ni * 16 + lrow) * 64 + ks + lk];
#pragma unroll
        for (int mi = 0; mi < 2; ++mi)
#pragma unroll
          for (int ni = 0; ni < 4; ++ni)
            acc[mi][ni] = __builtin_amdgcn_mfma_f32_16x16x32_bf16(
                av[mi], bv[ni], acc[mi][ni], 0, 0, 0);
      }
    }

    const int rbase = m0 + wr * 32 + (lane >> 4) * 4;
    const int cbase = n0 + wc * 64 + (lane & 15);
#pragma unroll
    for (int mi = 0; mi < 2; ++mi)
#pragma unroll
      for (int ni = 0; ni < 4; ++ni)
#pragma unroll
        for (int r = 0; r < 4; ++r)
          QKVb[(size_t)(rbase + mi * 16 + r) * ldc + cbase + ni * 16] =
              (__bf16)acc[mi][ni][r];
  }
}

// ---------------- megaB: attention + out-proj + LN -------------------------
// 512 blocks = exactly 2/CU: LDS 75776B (x2 = 151.5K <= 160K),
// launch_bounds(256,2) caps VGPR<=256.
__global__ __launch_bounds__(256, 2) void megaB(
    const __bf16* __restrict__ QKV, const float* __restrict__ lut,
    __bf16* __restrict__ Ctx, const __bf16* __restrict__ Wot,
    __bf16* __restrict__ OutB, const float* __restrict__ x,
    const float* __restrict__ bout, const float* __restrict__ gamma,
    const float* __restrict__ beta, float* __restrict__ y, unsigned* bar) {
  __shared__ alignas(16) char smem[75776];
  const int tid = threadIdx.x;
  const int bid = blockIdx.x;

  // ---- phase 0: band attention (R8-verbatim body, carved LDS) ----
  {
    __bf16* Qs = (__bf16*)(smem);            // 8192 B
    __bf16* Ks = (__bf16*)(smem + 8192);     // 16384 B
    __bf16* Ls = (__bf16*)(smem + 24576);    // 10240 B
    __bf16* VTs = (__bf16*)(smem + 34816);   // 24576 B
    __bf16* Ps = (__bf16*)(smem + 59392);    // 16384 B

    const int i0 = (bid & 15) * 64;
    const int h = (bid >> 4) & 15;
    const int b = bid >> 8;
    const size_t base = (size_t)b * 1024 * 3072 + (size_t)h * 64;

    for (int c = tid; c < 512; c += 256) {  // Q
      const int row = c >> 3, kb = (c & 7) * 16;
      bf16x8 v = *(const bf16x8*)(QKV + base + (size_t)(i0 + row) * 3072 + (c & 7) * 8);
      *(bf16x8*)((char*)Qs + row * 128 + (kb ^ ((row & 7) << 4))) = v;
    }
    for (int c = tid; c < 1024; c += 256) {  // K
      const int row = c >> 3, kb = (c & 7) * 16;
      int j = i0 - 32 + row;
      j = j < 0 ? 0 : (j > 1023 ? 1023 : j);
      bf16x8 v = *(const bf16x8*)(QKV + base + (size_t)j * 3072 + 1024 + (c & 7) * 8);
      *(bf16x8*)((char*)Ks + row * 128 + (kb ^ ((row & 7) << 4))) = v;
    }
    for (int c = tid; c < 1152; c += 256) {  // V -> VT (scalar writes)
      const int key = c >> 3, d0 = (c & 7) * 8;
      bf16x8 v;
      if (key < 128) {
        int j = i0 - 32 + key;
        j = j < 0 ? 0 : (j > 1023 ? 1023 : j);
        v = *(const bf16x8*)(QKV + base + (size_t)j * 3072 + 2048 + d0);
      } else {
        v = bf16x8{};
      }
#pragma unroll
      for (int e = 0; e < 8; ++e) {
        const int row = d0 + e;
        *(__bf16*)((char*)VTs + row * 384 + ((2 * key) ^ ((row & 7) << 4))) = v[e];
      }
    }
    for (int c = tid; c < 640; c += 256) {  // L
      const int row = c >> 3, d0 = (c & 7) * 8;
      bf16x8 o;
      if (row < 65) {
        const float* src = lut + (size_t)(991 + row) * 64 + d0;
#pragma unroll
        for (int e = 0; e < 8; ++e) o[e] = (__bf16)src[e];
      } else {
        o = bf16x8{};
      }
      *(bf16x8*)((char*)Ls + row * 128 + ((2 * d0) ^ ((row & 7) << 4))) = o;
    }
    __syncthreads();

    const int w = tid >> 6, lane = tid & 63;
    const int lr = lane & 15, lk = lane >> 4;
    char* Pw = (char*)Ps + w * 4096;

    bf16x8 aq[2];
    {
      const int row = w * 16 + lr, swz = (row & 7) << 4;
#pragma unroll
      for (int ks = 0; ks < 2; ++ks)
        aq[ks] = *(const bf16x8*)((const char*)Qs + row * 128 + ((ks * 64 + lk * 16) ^ swz));
    }

    f32x4 accs[5] = {};
    f32x4 accq[5] = {};
#pragma unroll
    for (int n = 0; n < 5; ++n) {
      const int krow = (w + n) * 16 + lr, ksz = (krow & 7) << 4;
      const int lrow = n * 16 + lr, lsz = (lrow & 7) << 4;
#pragma unroll
      for (int ks = 0; ks < 2; ++ks) {
        bf16x8 bk = *(const bf16x8*)((const char*)Ks + krow * 128 + ((ks * 64 + lk * 16) ^ ksz));
        accs[n] = __builtin_amdgcn_mfma_f32_16x16x32_bf16(aq[ks], bk, accs[n], 0, 0, 0);
        bf16x8 bl = *(const bf16x8*)((const char*)Ls + lrow * 128 + ((ks * 64 + lk * 16) ^ lsz));
        accq[n] = __builtin_amdgcn_mfma_f32_16x16x32_bf16(aq[ks], bl, accq[n], 0, 0, 0);
      }
    }

#pragma unroll
    for (int n = 0; n < 5; ++n)
#pragma unroll
      for (int r = 0; r < 4; ++r) {
        const int row = lk * 4 + r, col = n * 16 + lr;
        *(__bf16*)(Pw + row * 256 + ((2 * col) ^ ((row & 7) << 4))) = (__bf16)accq[n][r];
      }
    __syncthreads();

    float p[5][4], linv[4];
    {
      float sv[5][4], mrow[4], lsum[4];
#pragma unroll
      for (int reg = 0; reg < 4; ++reg) mrow[reg] = -1e30f;
#pragma unroll
      for (int n = 0; n < 5; ++n)
#pragma unroll
        for (int reg = 0; reg < 4; ++reg) {
          const int row = lk * 4 + reg;
          const int iq = w * 16 + row;
          const int jc = (w + n) * 16 + lr;
          const int r = jc - iq;
          const int j = i0 - 32 + jc;
          const int rc = r < 0 ? 0 : (r > 64 ? 64 : r);
          const float qe = (float)*(const __bf16*)(Pw + row * 256 + ((2 * rc) ^ ((row & 7) << 4)));
          const bool valid = (r >= 0) & (r <= 64) & (j >= 0) & (j <= 1023);
          const float s = valid ? (accs[n][reg] + qe) * 0.125f : -1e30f;
          sv[n][reg] = s;
          mrow[reg] = fmaxf(mrow[reg], s);
        }
#pragma unroll
      for (int reg = 0; reg < 4; ++reg) {
#pragma unroll
        for (int off = 1; off < 16; off <<= 1)
          mrow[reg] = fmaxf(mrow[reg], __shfl_xor(mrow[reg], off));
        lsum[reg] = 0.f;
      }
#pragma unroll
      for (int n = 0; n < 5; ++n)
#pragma unroll
        for (int reg = 0; reg < 4; ++reg) {
          const float e = __expf(sv[n][reg] - mrow[reg]);
          p[n][reg] = e;
          lsum[reg] += e;
        }
#pragma unroll
      for (int reg = 0; reg < 4; ++reg) {
#pragma unroll
        for (int off = 1; off < 16; off <<= 1)
          lsum[reg] += __shfl_xor(lsum[reg], off);
        linv[reg] = 1.0f / lsum[reg];
      }
    }

#pragma unroll
    for (int n = 0; n < 5; ++n)
#pragma unroll
      for (int r = 0; r < 4; ++r) {
        const int row = lk * 4 + r, col = n * 16 + lr;
        *(__bf16*)(Pw + row * 256 + ((2 * col) ^ ((row & 7) << 4))) = (__bf16)p[n][r];
      }
    *(uint2*)(Pw + lr * 256 + ((160 + lk * 8) ^ ((lr & 7) << 4))) = make_uint2(0u, 0u);
    __syncthreads();

    f32x4 acco[4] = {};
    bf16x8 ap[3];
    {
      const int row = lr, swz = (row & 7) << 4;
#pragma unroll
      for (int ks = 0; ks < 3; ++ks)
        ap[ks] = *(const bf16x8*)(Pw + row * 256 + ((ks * 64 + lk * 16) ^ swz));
    }
#pragma unroll
    for (int n = 0; n < 4; ++n) {
      const int vrow = n * 16 + lr, swz = (vrow & 7) << 4;
#pragma unroll
      for (int ks = 0; ks < 3; ++ks) {
        bf16x8 bv = *(const bf16x8*)((const char*)VTs + vrow * 384 +
                                     ((32 * w + ks * 64 + lk * 16) ^ swz));
        acco[n] = __builtin_amdgcn_mfma_f32_16x16x32_bf16(ap[ks], bv, acco[n], 0, 0, 0);
      }
    }

#pragma unroll
    for (int n = 0; n < 4; ++n)
#pragma unroll
      for (int reg = 0; reg < 4; ++reg) {
        const int row = lk * 4 + reg;
        const int i = i0 + w * 16 + row;
        const int d = n * 16 + lr;
        Ctx[(size_t)(b * 1024 + i) * 1024 + h * 64 + d] = (__bf16)(acco[n][reg] * linv[reg]);
      }
  }

  grid_barrier(bar, 512);

  // ---- phase 1: out-proj, 256 tiles on blocks 0..255 ----
  if (bid < 256) {
    __bf16* As = (__bf16*)(smem);
    __bf16* Bs = (__bf16*)(smem + 8192);
    const int m0 = (bid >> 3) * 64, n0 = (bid & 7) * 128;
    const int K = 1024, ldc = 1024;
    const int w = tid >> 6, lane = tid & 63;
    const int wr = w >> 1, wc = w & 1;
    const int lrow = lane & 15, lk = (lane >> 4) * 8;

    f32x4 acc[2][4] = {};

    for (int kt = 0; kt < K; kt += 64) {
      __syncthreads();
#pragma unroll
      for (int it = 0; it < 4; ++it) {
        const int c = it * 256 + tid;
        const int row = c >> 3;
        const int ko = (c & 7) * 8;
        if (row < 64)
          GLD_LDS(Ctx + (size_t)(m0 + row) * K + kt + ko, As + c * 8);
        GLD_LDS(Wot + (size_t)(n0 + row) * K + kt + ko, Bs + c * 8);
      }
      __syncthreads();
#pragma unroll
      for (int ks = 0; ks < 64; ks += 32) {
        bf16x8 av[2], bv[4];
#pragma unroll
        for (int mi = 0; mi < 2; ++mi)
          av[mi] = *(const bf16x8*)&As[(wr * 32 + mi * 16 + lrow) * 64 + ks + lk];
#pragma unroll
        for (int ni = 0; ni < 4; ++ni)
          bv[ni] = *(const bf16x8*)&Bs[(wc * 64 + ni * 16 + lrow) * 64 + ks + lk];
#pragma unroll
        for (int mi = 0; mi < 2; ++mi)
#pragma unroll
          for (int ni = 0; ni < 4; ++ni)
            acc[mi][ni] = __builtin_amdgcn_mfma_f32_16x16x32_bf16(
                av[mi], bv[ni], acc[mi][ni], 0, 0, 0);
      }
    }

    const int rbase = m0 + wr * 32 + (lane >> 4) * 4;
    const int cbase = n0 + wc * 64 + (lane & 15);
#pragma unroll
    for (int mi = 0; mi < 2; ++mi)
#pragma unroll
      for (int ni = 0; ni < 4; ++ni)
#pragma unroll
        for (int r = 0; r < 4; ++r)
          OutB[(size_t)(rbase + mi * 16 + r) * ldc + cbase + ni * 16] =
              (__bf16)acc[mi][ni][r];
  }

  grid_barrier(bar, 1024);

  // ---- phase 2: residual + bias + LayerNorm, 4 rows per block ----
  {
    float* red = (float*)smem;
    const int d0 = tid * 4;
    for (int k = 0; k < 4; ++k) {
      const int r = bid + k * 512;
      const size_t rb = (size_t)r * 1024 + d0;
      float4 xv = *(const float4*)(x + rb);
      bf16x4 ov = *(const bf16x4*)(OutB + rb);
      float4 bv = *(const float4*)(bout + d0);
      float v0 = xv.x + (float)ov[0] + bv.x;
      float v1 = xv.y + (float)ov[1] + bv.y;
      float v2 = xv.z + (float)ov[2] + bv.z;
      float v3 = xv.w + (float)ov[3] + bv.w;
      float s = v0 + v1 + v2 + v3;
      float ss = v0 * v0 + v1 * v1 + v2 * v2 + v3 * v3;
#pragma unroll
      for (int off = 32; off; off >>= 1) {
        s += __shfl_xor(s, off);
        ss += __shfl_xor(ss, off);
      }
      const int w = tid >> 6, lane = tid & 63;
      if (lane == 0) { red[w] = s; red[4 + w] = ss; }
      __syncthreads();
      s = red[0] + red[1] + red[2] + red[3];
      ss = red[4] + red[5] + red[6] + red[7];
      const float mu = s * (1.f / 1024.f);
      const float var = ss * (1.f / 1024.f) - mu * mu;
      const float rs = rsqrtf(var + 1e-5f);
      float4 gv = *(const float4*)(gamma + d0);
      float4 bev = *(const float4*)(beta + d0);
      float4 o;
      o.x = (v0 - mu) * rs * gv.x + bev.x;
      o.y = (v1 - mu) * rs * gv.y + bev.y;
      o.z = (v2 - mu) * rs * gv.z + bev.z;
      o.w = (v3 - mu) * rs * gv.w + bev.w;
      *(float4*)(y + rb) = o;
      __syncthreads();  // red reuse fence between rows
    }
  }
}

// ---------------------------------------------------------------------------
extern "C" void kernel_launch(void* const* d_in, const int* in_sizes, int n_in,
                              void* d_out, int out_size, void* d_ws, size_t ws_size,
                              hipStream_t stream) {
  const float* x     = (const float*)d_in[0];
  const float* ctxin = (const float*)d_in[1];
  const float* lut   = (const float*)d_in[2];
  const float* Wq    = (const float*)d_in[3];
  const float* Wk    = (const float*)d_in[4];
  const float* Wv    = (const float*)d_in[5];
  const float* Wo    = (const float*)d_in[6];
  const float* bo    = (const float*)d_in[7];
  const float* gam   = (const float*)d_in[8];
  const float* bet   = (const float*)d_in[9];
  float* out = (float*)d_out;

  char* ws = (char*)d_ws;
  __bf16* Xb    = (__bf16*)(ws);                        // 4 MB  [2048][1024]
  __bf16* Cb    = (__bf16*)(ws + ((size_t)4 << 20));    // 4 MB  [2048][1024]
  __bf16* Wqkvt = (__bf16*)(ws + ((size_t)8 << 20));    // 6 MB  [3072][1024]
  __bf16* Wot   = (__bf16*)(ws + ((size_t)14 << 20));   // 2 MB  [1024][1024]
  __bf16* QKVb  = (__bf16*)(ws + ((size_t)16 << 20));   // 12 MB [2048][3072]
  __bf16* CtxB  = (__bf16*)(ws + ((size_t)28 << 20));   // 4 MB  [2048][1024]
  __bf16* OutB  = (__bf16*)(ws + ((size_t)32 << 20));   // 4 MB  [2048][1024]
  unsigned* bar = (unsigned*)(ws + ((size_t)36 << 20)); // 2 counters

  hipMemsetAsync(bar, 0, 64, stream);

  megaA<<<768, 256, 0, stream>>>(x, ctxin, Wq, Wk, Wv, Wo, Xb, Cb, Wqkvt, Wot,
                                 QKVb, bar);

  megaB<<<512, 256, 0, stream>>>(QKVb, lut, CtxB, Wot, OutB, x, bo, gam, bet,
                                 out, bar + 1);
}

// Round 10
// 264.778 us; speedup vs baseline: 1.4721x; 1.4721x over previous
//
#include <hip/hip_runtime.h>
#include <hip/hip_bf16.h>
#include <cstdint>

// ---------------------------------------------------------------------------
// LocalMultiHeadAttention: B=2, T=1024, D=1024, H=16, dh=64, band=65 (half 32)
// 2-dispatch persistent megakernel (R9 structure).
// R9 post-mortem: acquire-scope atomic POLL emitted a cache invalidate per
// iteration (512 spinners -> chip-wide invalidation storm; MfmaUtil 0.96%,
// 215us megaB). Fix: relaxed poll + ONE fence after spin (standard pattern).
//   megaA (768 blocks, 3/CU): prep -> gbar -> QKV gemm
//   megaB (512 blocks, 2/CU): attn -> gbar -> out-proj -> gbar -> LN
// Ledger: BK=64 locked (R7). QKV 768-tile balance (R8). Flat-bid prep
// exonerated (R9 passed). Still quarantined: packed-V, CHUNKS loop.
// ---------------------------------------------------------------------------

typedef __bf16 bf16x8 __attribute__((ext_vector_type(8)));
typedef __bf16 bf16x4 __attribute__((ext_vector_type(4)));
typedef float f32x4 __attribute__((ext_vector_type(4)));

#define GLD_LDS(gptr, lptr)                                                    \
  __builtin_amdgcn_global_load_lds(                                            \
      (const __attribute__((address_space(1))) void*)(gptr),                   \
      (__attribute__((address_space(3))) void*)(lptr), 16, 0, 0)

// ---------------- device-scope grid barrier (relaxed poll) -----------------
__device__ __forceinline__ void grid_barrier(unsigned* cnt, unsigned target) {
  __syncthreads();
  if (threadIdx.x == 0) {
    __threadfence();  // release prior global writes (agent scope)
    __hip_atomic_fetch_add(cnt, 1u, __ATOMIC_RELAXED, __HIP_MEMORY_SCOPE_AGENT);
    // RELAXED poll: no per-iteration cache invalidate (R9 lesson).
    while (__hip_atomic_load(cnt, __ATOMIC_RELAXED, __HIP_MEMORY_SCOPE_AGENT) <
           target)
      __builtin_amdgcn_s_sleep(8);
    __threadfence();  // single acquire fence after spin exits
  }
  __syncthreads();
}

// ---------------- megaA: prep + QKV projection -----------------------------
// 768 blocks = exactly 3/CU: LDS 41216B x3 = 123.6K <= 160K; lb(256,3).
__global__ __launch_bounds__(256, 3) void megaA(
    const float* __restrict__ x, const float* __restrict__ ctxin,
    const float* __restrict__ Wq, const float* __restrict__ Wk,
    const float* __restrict__ Wv, const float* __restrict__ Wo,
    __bf16* __restrict__ Xb, __bf16* __restrict__ Cb,
    __bf16* __restrict__ Wqkvt, __bf16* __restrict__ Wot,
    __bf16* __restrict__ QKVb, unsigned* bar) {
  __shared__ float tile[64][65];
  __shared__ alignas(16) __bf16 As[64 * 64];
  __shared__ alignas(16) __bf16 Bs[128 * 64];
  const int tid = threadIdx.x;
  const int bid = blockIdx.x;

  // ---- phase 0: prep, 1536 units over 768 blocks (2 each) ----
  for (int u = bid; u < 1536; u += 768) {
    if (u < 1024) {  // weight transpose tile (proven prep2 z<4 body)
      const int z = u >> 8;
      const float* W = z == 0 ? Wq : z == 1 ? Wk : z == 2 ? Wv : Wo;
      __bf16* Wt = (z == 3) ? Wot : Wqkvt + (size_t)z * 1024 * 1024;
      const int k0 = ((u >> 4) & 15) * 64, n0 = (u & 15) * 64;
      const int tx = tid & 63, ty = tid >> 6;
#pragma unroll
      for (int r = ty; r < 64; r += 4)
        tile[r][tx] = W[(size_t)(k0 + r) * 1024 + n0 + tx];
      __syncthreads();
#pragma unroll
      for (int r = ty; r < 64; r += 4)
        Wt[(size_t)(n0 + r) * 1024 + k0 + tx] = (__bf16)tile[tx][r];
    } else {  // cvt (proven prep2 z>=4 body)
      const int c = u - 1024;  // 0..511
      const float* in = (c < 256) ? x : ctxin;
      __bf16* outp = (c < 256) ? Xb : Cb;
      const int base = (c & 255) * 2048;
#pragma unroll
      for (int it = 0; it < 8; ++it) {
        const int i = base + it * 256 + tid;
        float4 v = ((const float4*)in)[i];
        bf16x4 o;
        o[0] = (__bf16)v.x; o[1] = (__bf16)v.y;
        o[2] = (__bf16)v.z; o[3] = (__bf16)v.w;
        ((bf16x4*)outp)[i] = o;
      }
    }
    __syncthreads();  // tile reuse fence between prep units
  }

  grid_barrier(bar, 768);

  // ---- phase 1: QKV gemm, tile = bid (24 n-tiles x 32 m-tiles) ----
  {
    const int m0 = (bid / 24) * 64, n0 = (bid % 24) * 128;
    const __bf16* A = (n0 < 1024) ? Xb : Cb;
    const int K = 1024, ldc = 3072;
    const int w = tid >> 6, lane = tid & 63;
    const int wr = w >> 1, wc = w & 1;
    const int lrow = lane & 15, lk = (lane >> 4) * 8;

    f32x4 acc[2][4] = {};

    for (int kt = 0; kt < K; kt += 64) {
      __syncthreads();
#pragma unroll
      for (int it = 0; it < 4; ++it) {
        const int c = it * 256 + tid;
        const int row = c >> 3;
        const int ko = (c & 7) * 8;
        if (row < 64)  // wave-uniform A guard (R6/R8-proven)
          GLD_LDS(A + (size_t)(m0 + row) * K + kt + ko, As + c * 8);
        GLD_LDS(Wqkvt + (size_t)(n0 + row) * K + kt + ko, Bs + c * 8);
      }
      __syncthreads();
#pragma unroll
      for (int ks = 0; ks < 64; ks += 32) {
        bf16x8 av[2], bv[4];
#pragma unroll
        for (int mi = 0; mi < 2; ++mi)
          av[mi] = *(const bf16x8*)&As[(wr * 32 + mi * 16 + lrow) * 64 + ks + lk];
#pragma unroll
        for (int ni = 0; ni < 4; ++ni)
          bv[ni] = *(const bf16x8*)&Bs[(wc * 64 + ni * 16 + lrow) * 64 + ks + lk];
#pragma unroll
        for (int mi = 0; mi < 2; ++mi)
#pragma unroll
          for (int ni = 0; ni < 4; ++ni)
            acc[mi][ni] = __builtin_amdgcn_mfma_f32_16x16x32_bf16(
                av[mi], bv[ni], acc[mi][ni], 0, 0, 0);
      }
    }

    const int rbase = m0 + wr * 32 + (lane >> 4) * 4;
    const int cbase = n0 + wc * 64 + (lane & 15);
#pragma unroll
    for (int mi = 0; mi < 2; ++mi)
#pragma unroll
      for (int ni = 0; ni < 4; ++ni)
#pragma unroll
        for (int r = 0; r < 4; ++r)
          QKVb[(size_t)(rbase + mi * 16 + r) * ldc + cbase + ni * 16] =
              (__bf16)acc[mi][ni][r];
  }
}

// ---------------- megaB: attention + out-proj + LN -------------------------
// 512 blocks = exactly 2/CU: LDS 75776B x2 = 151.5K <= 160K; lb(256,2).
__global__ __launch_bounds__(256, 2) void megaB(
    const __bf16* __restrict__ QKV, const float* __restrict__ lut,
    __bf16* __restrict__ Ctx, const __bf16* __restrict__ Wot,
    __bf16* __restrict__ OutB, const float* __restrict__ x,
    const float* __restrict__ bout, const float* __restrict__ gamma,
    const float* __restrict__ beta, float* __restrict__ y, unsigned* bar) {
  __shared__ alignas(16) char smem[75776];
  const int tid = threadIdx.x;
  const int bid = blockIdx.x;

  // ---- phase 0: band attention (R8-verbatim body, carved LDS) ----
  {
    __bf16* Qs = (__bf16*)(smem);            // 8192 B
    __bf16* Ks = (__bf16*)(smem + 8192);     // 16384 B
    __bf16* Ls = (__bf16*)(smem + 24576);    // 10240 B
    __bf16* VTs = (__bf16*)(smem + 34816);   // 24576 B
    __bf16* Ps = (__bf16*)(smem + 59392);    // 16384 B

    const int i0 = (bid & 15) * 64;
    const int h = (bid >> 4) & 15;
    const int b = bid >> 8;
    const size_t base = (size_t)b * 1024 * 3072 + (size_t)h * 64;

    for (int c = tid; c < 512; c += 256) {  // Q
      const int row = c >> 3, kb = (c & 7) * 16;
      bf16x8 v = *(const bf16x8*)(QKV + base + (size_t)(i0 + row) * 3072 + (c & 7) * 8);
      *(bf16x8*)((char*)Qs + row * 128 + (kb ^ ((row & 7) << 4))) = v;
    }
    for (int c = tid; c < 1024; c += 256) {  // K
      const int row = c >> 3, kb = (c & 7) * 16;
      int j = i0 - 32 + row;
      j = j < 0 ? 0 : (j > 1023 ? 1023 : j);
      bf16x8 v = *(const bf16x8*)(QKV + base + (size_t)j * 3072 + 1024 + (c & 7) * 8);
      *(bf16x8*)((char*)Ks + row * 128 + (kb ^ ((row & 7) << 4))) = v;
    }
    for (int c = tid; c < 1152; c += 256) {  // V -> VT (scalar writes)
      const int key = c >> 3, d0 = (c & 7) * 8;
      bf16x8 v;
      if (key < 128) {
        int j = i0 - 32 + key;
        j = j < 0 ? 0 : (j > 1023 ? 1023 : j);
        v = *(const bf16x8*)(QKV + base + (size_t)j * 3072 + 2048 + d0);
      } else {
        v = bf16x8{};
      }
#pragma unroll
      for (int e = 0; e < 8; ++e) {
        const int row = d0 + e;
        *(__bf16*)((char*)VTs + row * 384 + ((2 * key) ^ ((row & 7) << 4))) = v[e];
      }
    }
    for (int c = tid; c < 640; c += 256) {  // L
      const int row = c >> 3, d0 = (c & 7) * 8;
      bf16x8 o;
      if (row < 65) {
        const float* src = lut + (size_t)(991 + row) * 64 + d0;
#pragma unroll
        for (int e = 0; e < 8; ++e) o[e] = (__bf16)src[e];
      } else {
        o = bf16x8{};
      }
      *(bf16x8*)((char*)Ls + row * 128 + ((2 * d0) ^ ((row & 7) << 4))) = o;
    }
    __syncthreads();

    const int w = tid >> 6, lane = tid & 63;
    const int lr = lane & 15, lk = lane >> 4;
    char* Pw = (char*)Ps + w * 4096;

    bf16x8 aq[2];
    {
      const int row = w * 16 + lr, swz = (row & 7) << 4;
#pragma unroll
      for (int ks = 0; ks < 2; ++ks)
        aq[ks] = *(const bf16x8*)((const char*)Qs + row * 128 + ((ks * 64 + lk * 16) ^ swz));
    }

    f32x4 accs[5] = {};
    f32x4 accq[5] = {};
#pragma unroll
    for (int n = 0; n < 5; ++n) {
      const int krow = (w + n) * 16 + lr, ksz = (krow & 7) << 4;
      const int lrow = n * 16 + lr, lsz = (lrow & 7) << 4;
#pragma unroll
      for (int ks = 0; ks < 2; ++ks) {
        bf16x8 bk = *(const bf16x8*)((const char*)Ks + krow * 128 + ((ks * 64 + lk * 16) ^ ksz));
        accs[n] = __builtin_amdgcn_mfma_f32_16x16x32_bf16(aq[ks], bk, accs[n], 0, 0, 0);
        bf16x8 bl = *(const bf16x8*)((const char*)Ls + lrow * 128 + ((ks * 64 + lk * 16) ^ lsz));
        accq[n] = __builtin_amdgcn_mfma_f32_16x16x32_bf16(aq[ks], bl, accq[n], 0, 0, 0);
      }
    }

#pragma unroll
    for (int n = 0; n < 5; ++n)
#pragma unroll
      for (int r = 0; r < 4; ++r) {
        const int row = lk * 4 + r, col = n * 16 + lr;
        *(__bf16*)(Pw + row * 256 + ((2 * col) ^ ((row & 7) << 4))) = (__bf16)accq[n][r];
      }
    __syncthreads();

    float p[5][4], linv[4];
    {
      float sv[5][4], mrow[4], lsum[4];
#pragma unroll
      for (int reg = 0; reg < 4; ++reg) mrow[reg] = -1e30f;
#pragma unroll
      for (int n = 0; n < 5; ++n)
#pragma unroll
        for (int reg = 0; reg < 4; ++reg) {
          const int row = lk * 4 + reg;
          const int iq = w * 16 + row;
          const int jc = (w + n) * 16 + lr;
          const int r = jc - iq;
          const int j = i0 - 32 + jc;
          const int rc = r < 0 ? 0 : (r > 64 ? 64 : r);
          const float qe = (float)*(const __bf16*)(Pw + row * 256 + ((2 * rc) ^ ((row & 7) << 4)));
          const bool valid = (r >= 0) & (r <= 64) & (j >= 0) & (j <= 1023);
          const float s = valid ? (accs[n][reg] + qe) * 0.125f : -1e30f;
          sv[n][reg] = s;
          mrow[reg] = fmaxf(mrow[reg], s);
        }
#pragma unroll
      for (int reg = 0; reg < 4; ++reg) {
#pragma unroll
        for (int off = 1; off < 16; off <<= 1)
          mrow[reg] = fmaxf(mrow[reg], __shfl_xor(mrow[reg], off));
        lsum[reg] = 0.f;
      }
#pragma unroll
      for (int n = 0; n < 5; ++n)
#pragma unroll
        for (int reg = 0; reg < 4; ++reg) {
          const float e = __expf(sv[n][reg] - mrow[reg]);
          p[n][reg] = e;
          lsum[reg] += e;
        }
#pragma unroll
      for (int reg = 0; reg < 4; ++reg) {
#pragma unroll
        for (int off = 1; off < 16; off <<= 1)
          lsum[reg] += __shfl_xor(lsum[reg], off);
        linv[reg] = 1.0f / lsum[reg];
      }
    }

#pragma unroll
    for (int n = 0; n < 5; ++n)
#pragma unroll
      for (int r = 0; r < 4; ++r) {
        const int row = lk * 4 + r, col = n * 16 + lr;
        *(__bf16*)(Pw + row * 256 + ((2 * col) ^ ((row & 7) << 4))) = (__bf16)p[n][r];
      }
    *(uint2*)(Pw + lr * 256 + ((160 + lk * 8) ^ ((lr & 7) << 4))) = make_uint2(0u, 0u);
    __syncthreads();

    f32x4 acco[4] = {};
    bf16x8 ap[3];
    {
      const int row = lr, swz = (row & 7) << 4;
#pragma unroll
      for (int ks = 0; ks < 3; ++ks)
        ap[ks] = *(const bf16x8*)(Pw + row * 256 + ((ks * 64 + lk * 16) ^ swz));
    }
#pragma unroll
    for (int n = 0; n < 4; ++n) {
      const int vrow = n * 16 + lr, swz = (vrow & 7) << 4;
#pragma unroll
      for (int ks = 0; ks < 3; ++ks) {
        bf16x8 bv = *(const bf16x8*)((const char*)VTs + vrow * 384 +
                                     ((32 * w + ks * 64 + lk * 16) ^ swz));
        acco[n] = __builtin_amdgcn_mfma_f32_16x16x32_bf16(ap[ks], bv, acco[n], 0, 0, 0);
      }
    }

#pragma unroll
    for (int n = 0; n < 4; ++n)
#pragma unroll
      for (int reg = 0; reg < 4; ++reg) {
        const int row = lk * 4 + reg;
        const int i = i0 + w * 16 + row;
        const int d = n * 16 + lr;
        Ctx[(size_t)(b * 1024 + i) * 1024 + h * 64 + d] = (__bf16)(acco[n][reg] * linv[reg]);
      }
  }

  grid_barrier(bar, 512);

  // ---- phase 1: out-proj, 256 tiles on blocks 0..255 ----
  if (bid < 256) {
    __bf16* As = (__bf16*)(smem);
    __bf16* Bs = (__bf16*)(smem + 8192);
    const int m0 = (bid >> 3) * 64, n0 = (bid & 7) * 128;
    const int K = 1024, ldc = 1024;
    const int w = tid >> 6, lane = tid & 63;
    const int wr = w >> 1, wc = w & 1;
    const int lrow = lane & 15, lk = (lane >> 4) * 8;

    f32x4 acc[2][4] = {};

    for (int kt = 0; kt < K; kt += 64) {
      __syncthreads();
#pragma unroll
      for (int it = 0; it < 4; ++it) {
        const int c = it * 256 + tid;
        const int row = c >> 3;
        const int ko = (c & 7) * 8;
        if (row < 64)
          GLD_LDS(Ctx + (size_t)(m0 + row) * K + kt + ko, As + c * 8);
        GLD_LDS(Wot + (size_t)(n0 + row) * K + kt + ko, Bs + c * 8);
      }
      __syncthreads();
#pragma unroll
      for (int ks = 0; ks < 64; ks += 32) {
        bf16x8 av[2], bv[4];
#pragma unroll
        for (int mi = 0; mi < 2; ++mi)
          av[mi] = *(const bf16x8*)&As[(wr * 32 + mi * 16 + lrow) * 64 + ks + lk];
#pragma unroll
        for (int ni = 0; ni < 4; ++ni)
          bv[ni] = *(const bf16x8*)&Bs[(wc * 64 + ni * 16 + lrow) * 64 + ks + lk];
#pragma unroll
        for (int mi = 0; mi < 2; ++mi)
#pragma unroll
          for (int ni = 0; ni < 4; ++ni)
            acc[mi][ni] = __builtin_amdgcn_mfma_f32_16x16x32_bf16(
                av[mi], bv[ni], acc[mi][ni], 0, 0, 0);
      }
    }

    const int rbase = m0 + wr * 32 + (lane >> 4) * 4;
    const int cbase = n0 + wc * 64 + (lane & 15);
#pragma unroll
    for (int mi = 0; mi < 2; ++mi)
#pragma unroll
      for (int ni = 0; ni < 4; ++ni)
#pragma unroll
        for (int r = 0; r < 4; ++r)
          OutB[(size_t)(rbase + mi * 16 + r) * ldc + cbase + ni * 16] =
              (__bf16)acc[mi][ni][r];
  }

  grid_barrier(bar, 1024);

  // ---- phase 2: residual + bias + LayerNorm, 4 rows per block ----
  {
    float* red = (float*)smem;
    const int d0 = tid * 4;
    for (int k = 0; k < 4; ++k) {
      const int r = bid + k * 512;
      const size_t rb = (size_t)r * 1024 + d0;
      float4 xv = *(const float4*)(x + rb);
      bf16x4 ov = *(const bf16x4*)(OutB + rb);
      float4 bv = *(const float4*)(bout + d0);
      float v0 = xv.x + (float)ov[0] + bv.x;
      float v1 = xv.y + (float)ov[1] + bv.y;
      float v2 = xv.z + (float)ov[2] + bv.z;
      float v3 = xv.w + (float)ov[3] + bv.w;
      float s = v0 + v1 + v2 + v3;
      float ss = v0 * v0 + v1 * v1 + v2 * v2 + v3 * v3;
#pragma unroll
      for (int off = 32; off; off >>= 1) {
        s += __shfl_xor(s, off);
        ss += __shfl_xor(ss, off);
      }
      const int w = tid >> 6, lane = tid & 63;
      if (lane == 0) { red[w] = s; red[4 + w] = ss; }
      __syncthreads();
      s = red[0] + red[1] + red[2] + red[3];
      ss = red[4] + red[5] + red[6] + red[7];
      const float mu = s * (1.f / 1024.f);
      const float var = ss * (1.f / 1024.f) - mu * mu;
      const float rs = rsqrtf(var + 1e-5f);
      float4 gv = *(const float4*)(gamma + d0);
      float4 bev = *(const float4*)(beta + d0);
      float4 o;
      o.x = (v0 - mu) * rs * gv.x + bev.x;
      o.y = (v1 - mu) * rs * gv.y + bev.y;
      o.z = (v2 - mu) * rs * gv.z + bev.z;
      o.w = (v3 - mu) * rs * gv.w + bev.w;
      *(float4*)(y + rb) = o;
      __syncthreads();  // red reuse fence between rows
    }
  }
}

// ---------------------------------------------------------------------------
extern "C" void kernel_launch(void* const* d_in, const int* in_sizes, int n_in,
                              void* d_out, int out_size, void* d_ws, size_t ws_size,
                              hipStream_t stream) {
  const float* x     = (const float*)d_in[0];
  const float* ctxin = (const float*)d_in[1];
  const float* lut   = (const float*)d_in[2];
  const float* Wq    = (const float*)d_in[3];
  const float* Wk    = (const float*)d_in[4];
  const float* Wv    = (const float*)d_in[5];
  const float* Wo    = (const float*)d_in[6];
  const float* bo    = (const float*)d_in[7];
  const float* gam   = (const float*)d_in[8];
  const float* bet   = (const float*)d_in[9];
  float* out = (float*)d_out;

  char* ws = (char*)d_ws;
  __bf16* Xb    = (__bf16*)(ws);                        // 4 MB  [2048][1024]
  __bf16* Cb    = (__bf16*)(ws + ((size_t)4 << 20));    // 4 MB  [2048][1024]
  __bf16* Wqkvt = (__bf16*)(ws + ((size_t)8 << 20));    // 6 MB  [3072][1024]
  __bf16* Wot   = (__bf16*)(ws + ((size_t)14 << 20));   // 2 MB  [1024][1024]
  __bf16* QKVb  = (__bf16*)(ws + ((size_t)16 << 20));   // 12 MB [2048][3072]
  __bf16* CtxB  = (__bf16*)(ws + ((size_t)28 << 20));   // 4 MB  [2048][1024]
  __bf16* OutB  = (__bf16*)(ws + ((size_t)32 << 20));   // 4 MB  [2048][1024]
  unsigned* bar = (unsigned*)(ws + ((size_t)36 << 20)); // 2 counters

  hipMemsetAsync(bar, 0, 64, stream);

  megaA<<<768, 256, 0, stream>>>(x, ctxin, Wq, Wk, Wv, Wo, Xb, Cb, Wqkvt, Wot,
                                 QKVb, bar);

  megaB<<<512, 256, 0, stream>>>(QKVb, lut, CtxB, Wot, OutB, x, bo, gam, bet,
                                 out, bar + 1);
}

// Round 11
// 66.605 us; speedup vs baseline: 5.8522x; 3.9754x over previous
//
#include <hip/hip_runtime.h>
#include <hip/hip_bf16.h>
#include <cstdint>

// ---------------------------------------------------------------------------
// LocalMultiHeadAttention: B=2, T=1024, D=1024, H=16, dh=64, band=65 (half 32)
// R8 5-dispatch structure (last-known-good 76us) + T2 LDS swizzle in GEMM.
// R10 counters exposed SQ_LDS_BANK_CONFLICT=7.1M in the GEMM: ds_read_b128
// fragment reads have 16 lanes reading 16 rows (stride 128B) at one column
// = 16-way bank conflict (5.7x, m136). Fix per rule #21 (m201 pattern):
// linear LDS dest (gld_lds requirement) + pre-swizzled GLOBAL source chunk
// (ko = (cc ^ (row&7))*8) + swizzled read (byte ^ ((row&7)<<4)).
// Ledger: BK=64 locked (R7). QKV 768-block balance (R8). Megakernel shelved
// (R9 acquire-poll storm; R10 relaxed-poll staleness). Quarantined: packed-V,
// CHUNKS loop. Flat-bid prep exonerated (R9).
// ---------------------------------------------------------------------------

typedef __bf16 bf16x8 __attribute__((ext_vector_type(8)));
typedef __bf16 bf16x4 __attribute__((ext_vector_type(4)));
typedef float f32x4 __attribute__((ext_vector_type(4)));

#define GLD_LDS(gptr, lptr)                                                    \
  __builtin_amdgcn_global_load_lds(                                            \
      (const __attribute__((address_space(1))) void*)(gptr),                   \
      (__attribute__((address_space(3))) void*)(lptr), 16, 0, 0)

// ---------------- 1. prep2: weight transposes (z<4) + cvt (z=4,5) ----------
__global__ __launch_bounds__(256) void prep2(
    const float* __restrict__ x, const float* __restrict__ ctxin,
    const float* __restrict__ Wq, const float* __restrict__ Wk,
    const float* __restrict__ Wv, const float* __restrict__ Wo,
    __bf16* __restrict__ Xb, __bf16* __restrict__ Cb,
    __bf16* __restrict__ Wqkvt, __bf16* __restrict__ Wot) {
  __shared__ float tile[64][65];
  const int z = blockIdx.z;
  if (z < 4) {  // transpose+cvt one 64x64 tile (R3-exact body)
    const float* W = z == 0 ? Wq : z == 1 ? Wk : z == 2 ? Wv : Wo;
    __bf16* Wt = (z == 3) ? Wot : Wqkvt + (size_t)z * 1024 * 1024;
    const int k0 = blockIdx.x * 64, n0 = blockIdx.y * 64;
    const int tx = threadIdx.x & 63, ty = threadIdx.x >> 6;
#pragma unroll
    for (int r = ty; r < 64; r += 4)
      tile[r][tx] = W[(size_t)(k0 + r) * 1024 + n0 + tx];
    __syncthreads();
#pragma unroll
    for (int r = ty; r < 64; r += 4)
      Wt[(size_t)(n0 + r) * 1024 + k0 + tx] = (__bf16)tile[tx][r];
  } else {  // cvt: 256 blocks x 8 float4/thread per tensor
    const float* in = (z == 4) ? x : ctxin;
    __bf16* out = (z == 4) ? Xb : Cb;
    const int base = (blockIdx.y * 16 + blockIdx.x) * 2048;
#pragma unroll
    for (int it = 0; it < 8; ++it) {
      const int i = base + it * 256 + threadIdx.x;
      float4 v = ((const float4*)in)[i];
      bf16x4 o;
      o[0] = (__bf16)v.x; o[1] = (__bf16)v.y; o[2] = (__bf16)v.z; o[3] = (__bf16)v.w;
      ((bf16x4*)out)[i] = o;
    }
  }
}

// ---------------- 2/4. bf16 GEMM (R8 template + T2 swizzle) ----------------
// BM x 128 tile, BK=64, 4 waves (2x2), mfma 16x16x32, global_load_lds w16.
// Swizzle: LDS chunk (row, cc) holds global chunk (row, cc^(row&7));
// fragment reads XOR byte offset with (row&7)<<4. 16-way -> 2-way (free).
template <int BM>
__global__ __launch_bounds__(256) void gemm_bf16(
    const __bf16* __restrict__ A0, const __bf16* __restrict__ A1, int nsplit,
    const __bf16* __restrict__ Bt, __bf16* __restrict__ C, int K, int ldc) {
  constexpr int MR = BM / 32;  // acc rows per wave (wave grid is 2x2)
  __shared__ alignas(16) __bf16 As[BM * 64];
  __shared__ alignas(16) __bf16 Bs[128 * 64];
  const int tid = threadIdx.x;
  const int m0 = blockIdx.y * BM, n0 = blockIdx.x * 128;
  const __bf16* A = (n0 < nsplit) ? A0 : A1;
  const int w = tid >> 6, lane = tid & 63;
  const int wr = w >> 1, wc = w & 1;
  const int lrow = lane & 15, lk = (lane >> 4) * 8;

  f32x4 acc[MR][4] = {};

  for (int kt = 0; kt < K; kt += 64) {
    __syncthreads();
#pragma unroll
    for (int it = 0; it < 4; ++it) {
      const int c = it * 256 + tid;          // 0..1023 chunk id (16B each)
      const int row = c >> 3;                // 0..127
      const int ko = (((c & 7) ^ (row & 7)) * 8);  // pre-swizzled src chunk
      if (row < BM)  // wave-uniform; always true for BM=128
        GLD_LDS(A + (size_t)(m0 + row) * K + kt + ko, As + c * 8);
      GLD_LDS(Bt + (size_t)(n0 + row) * K + kt + ko, Bs + c * 8);
    }
    __syncthreads();
#pragma unroll
    for (int ks = 0; ks < 64; ks += 32) {
      bf16x8 av[MR], bv[4];
#pragma unroll
      for (int mi = 0; mi < MR; ++mi) {
        const int arow = wr * (MR * 16) + mi * 16 + lrow;
        av[mi] = *(const bf16x8*)((const char*)As + arow * 128 +
                                  (((ks + lk) * 2) ^ ((arow & 7) << 4)));
      }
#pragma unroll
      for (int ni = 0; ni < 4; ++ni) {
        const int brow = wc * 64 + ni * 16 + lrow;
        bv[ni] = *(const bf16x8*)((const char*)Bs + brow * 128 +
                                  (((ks + lk) * 2) ^ ((brow & 7) << 4)));
      }
#pragma unroll
      for (int mi = 0; mi < MR; ++mi)
#pragma unroll
        for (int ni = 0; ni < 4; ++ni)
          acc[mi][ni] = __builtin_amdgcn_mfma_f32_16x16x32_bf16(
              av[mi], bv[ni], acc[mi][ni], 0, 0, 0);
    }
  }

  const int rbase = m0 + wr * (MR * 16) + (lane >> 4) * 4;
  const int cbase = n0 + wc * 64 + (lane & 15);
#pragma unroll
  for (int mi = 0; mi < MR; ++mi)
#pragma unroll
    for (int ni = 0; ni < 4; ++ni)
#pragma unroll
      for (int r = 0; r < 4; ++r)
        C[(size_t)(rbase + mi * 16 + r) * ldc + cbase + ni * 16] =
            (__bf16)acc[mi][ni][r];
}

// ---------------- 3. band attention v3 [R8-exact] --------------------------
__global__ __launch_bounds__(256) void attn_band_v3(
    const __bf16* __restrict__ QKV,  // [2048][3072]: Q | K | V
    const float* __restrict__ lut,   // [2047][64]
    __bf16* __restrict__ Ctx) {      // [2048][1024]
  __shared__ alignas(16) __bf16 Qs[64 * 64];
  __shared__ alignas(16) __bf16 Ks[128 * 64];
  __shared__ alignas(16) __bf16 Ls[80 * 64];
  __shared__ alignas(16) __bf16 VTs[64 * 192];
  __shared__ alignas(16) __bf16 Ps[4 * 16 * 128];

  const int tid = threadIdx.x;
  const int i0 = blockIdx.x * 64;
  const int h = blockIdx.y;
  const int b = blockIdx.z;
  const size_t base = (size_t)b * 1024 * 3072 + (size_t)h * 64;

  // ---- staging ----
  for (int c = tid; c < 512; c += 256) {  // Q
    const int row = c >> 3, kb = (c & 7) * 16;
    bf16x8 v = *(const bf16x8*)(QKV + base + (size_t)(i0 + row) * 3072 + (c & 7) * 8);
    *(bf16x8*)((char*)Qs + row * 128 + (kb ^ ((row & 7) << 4))) = v;
  }
  for (int c = tid; c < 1024; c += 256) {  // K
    const int row = c >> 3, kb = (c & 7) * 16;
    int j = i0 - 32 + row;
    j = j < 0 ? 0 : (j > 1023 ? 1023 : j);
    bf16x8 v = *(const bf16x8*)(QKV + base + (size_t)j * 3072 + 1024 + (c & 7) * 8);
    *(bf16x8*)((char*)Ks + row * 128 + (kb ^ ((row & 7) << 4))) = v;
  }
  for (int c = tid; c < 1152; c += 256) {  // V -> VT (scalar writes)
    const int key = c >> 3, d0 = (c & 7) * 8;
    bf16x8 v;
    if (key < 128) {
      int j = i0 - 32 + key;
      j = j < 0 ? 0 : (j > 1023 ? 1023 : j);
      v = *(const bf16x8*)(QKV + base + (size_t)j * 3072 + 2048 + d0);
    } else {
      v = bf16x8{};  // zero pad keys 128..143
    }
#pragma unroll
    for (int e = 0; e < 8; ++e) {
      const int row = d0 + e;
      *(__bf16*)((char*)VTs + row * 384 + ((2 * key) ^ ((row & 7) << 4))) = v[e];
    }
  }
  for (int c = tid; c < 640; c += 256) {  // L rows 0..64 real, 65..79 zero
    const int row = c >> 3, d0 = (c & 7) * 8;
    bf16x8 o;
    if (row < 65) {
      const float* src = lut + (size_t)(991 + row) * 64 + d0;
#pragma unroll
      for (int e = 0; e < 8; ++e) o[e] = (__bf16)src[e];
    } else {
      o = bf16x8{};
    }
    *(bf16x8*)((char*)Ls + row * 128 + ((2 * d0) ^ ((row & 7) << 4))) = o;
  }
  __syncthreads();

  const int w = tid >> 6, lane = tid & 63;
  const int lr = lane & 15, lk = lane >> 4;
  char* Pw = (char*)(Ps + w * 16 * 128);

  bf16x8 aq[2];
  {
    const int row = w * 16 + lr, swz = (row & 7) << 4;
#pragma unroll
    for (int ks = 0; ks < 2; ++ks)
      aq[ks] = *(const bf16x8*)((const char*)Qs + row * 128 + ((ks * 64 + lk * 16) ^ swz));
  }

  // ---- S = Q.K^T and QE = Q.L^T ----
  f32x4 accs[5] = {};
  f32x4 accq[5] = {};
#pragma unroll
  for (int n = 0; n < 5; ++n) {
    const int krow = (w + n) * 16 + lr, ksz = (krow & 7) << 4;
    const int lrow2 = n * 16 + lr, lsz = (lrow2 & 7) << 4;
#pragma unroll
    for (int ks = 0; ks < 2; ++ks) {
      bf16x8 bk = *(const bf16x8*)((const char*)Ks + krow * 128 + ((ks * 64 + lk * 16) ^ ksz));
      accs[n] = __builtin_amdgcn_mfma_f32_16x16x32_bf16(aq[ks], bk, accs[n], 0, 0, 0);
      bf16x8 bl = *(const bf16x8*)((const char*)Ls + lrow2 * 128 + ((ks * 64 + lk * 16) ^ lsz));
      accq[n] = __builtin_amdgcn_mfma_f32_16x16x32_bf16(aq[ks], bl, accq[n], 0, 0, 0);
    }
  }

  // ---- QE -> per-wave LDS ----
#pragma unroll
  for (int n = 0; n < 5; ++n)
#pragma unroll
    for (int r = 0; r < 4; ++r) {
      const int row = lk * 4 + r, col = n * 16 + lr;
      *(__bf16*)(Pw + row * 256 + ((2 * col) ^ ((row & 7) << 4))) = (__bf16)accq[n][r];
    }
  __syncthreads();

  // ---- combine skew + mask + softmax ----
  float p[5][4], linv[4];
  {
    float sv[5][4], mrow[4], lsum[4];
#pragma unroll
    for (int reg = 0; reg < 4; ++reg) mrow[reg] = -1e30f;
#pragma unroll
    for (int n = 0; n < 5; ++n)
#pragma unroll
      for (int reg = 0; reg < 4; ++reg) {
        const int row = lk * 4 + reg;
        const int iq = w * 16 + row;
        const int jc = (w + n) * 16 + lr;
        const int r = jc - iq;
        const int j = i0 - 32 + jc;
        const int rc = r < 0 ? 0 : (r > 64 ? 64 : r);
        const float qe = (float)*(const __bf16*)(Pw + row * 256 + ((2 * rc) ^ ((row & 7) << 4)));
        const bool valid = (r >= 0) & (r <= 64) & (j >= 0) & (j <= 1023);
        const float s = valid ? (accs[n][reg] + qe) * 0.125f : -1e30f;
        sv[n][reg] = s;
        mrow[reg] = fmaxf(mrow[reg], s);
      }
#pragma unroll
    for (int reg = 0; reg < 4; ++reg) {
#pragma unroll
      for (int off = 1; off < 16; off <<= 1)
        mrow[reg] = fmaxf(mrow[reg], __shfl_xor(mrow[reg], off));
      lsum[reg] = 0.f;
    }
#pragma unroll
    for (int n = 0; n < 5; ++n)
#pragma unroll
      for (int reg = 0; reg < 4; ++reg) {
        const float e = __expf(sv[n][reg] - mrow[reg]);
        p[n][reg] = e;
        lsum[reg] += e;
      }
#pragma unroll
    for (int reg = 0; reg < 4; ++reg) {
#pragma unroll
      for (int off = 1; off < 16; off <<= 1)
        lsum[reg] += __shfl_xor(lsum[reg], off);
      linv[reg] = 1.0f / lsum[reg];
    }
  }

  // ---- P -> LDS ----
#pragma unroll
  for (int n = 0; n < 5; ++n)
#pragma unroll
    for (int r = 0; r < 4; ++r) {
      const int row = lk * 4 + r, col = n * 16 + lr;
      *(__bf16*)(Pw + row * 256 + ((2 * col) ^ ((row & 7) << 4))) = (__bf16)p[n][r];
    }
  *(uint2*)(Pw + lr * 256 + ((160 + lk * 8) ^ ((lr & 7) << 4))) = make_uint2(0u, 0u);
  __syncthreads();

  // ---- PV ----
  f32x4 acco[4] = {};
  bf16x8 ap[3];
  {
    const int row = lr, swz = (row & 7) << 4;
#pragma unroll
    for (int ks = 0; ks < 3; ++ks)
      ap[ks] = *(const bf16x8*)(Pw + row * 256 + ((ks * 64 + lk * 16) ^ swz));
  }
#pragma unroll
  for (int n = 0; n < 4; ++n) {
    const int vrow = n * 16 + lr, swz = (vrow & 7) << 4;
#pragma unroll
    for (int ks = 0; ks < 3; ++ks) {
      bf16x8 bv = *(const bf16x8*)((const char*)VTs + vrow * 384 +
                                   ((32 * w + ks * 64 + lk * 16) ^ swz));
      acco[n] = __builtin_amdgcn_mfma_f32_16x16x32_bf16(ap[ks], bv, acco[n], 0, 0, 0);
    }
  }

#pragma unroll
  for (int n = 0; n < 4; ++n)
#pragma unroll
    for (int reg = 0; reg < 4; ++reg) {
      const int row = lk * 4 + reg;
      const int i = i0 + w * 16 + row;
      const int d = n * 16 + lr;
      Ctx[(size_t)(b * 1024 + i) * 1024 + h * 64 + d] = (__bf16)(acco[n][reg] * linv[reg]);
    }
}

// ---------------- 5. residual + bias + LayerNorm (vectorized) --------------
__global__ __launch_bounds__(256) void ln_residual(
    const float* __restrict__ x, const __bf16* __restrict__ outb,
    const float* __restrict__ bout, const float* __restrict__ gamma,
    const float* __restrict__ beta, float* __restrict__ y) {
  const int r = blockIdx.x;
  const int tid = threadIdx.x;
  const int d0 = tid * 4;
  const size_t rb = (size_t)r * 1024 + d0;
  float4 xv = *(const float4*)(x + rb);
  bf16x4 ov = *(const bf16x4*)(outb + rb);
  float4 bv = *(const float4*)(bout + d0);
  float v0 = xv.x + (float)ov[0] + bv.x;
  float v1 = xv.y + (float)ov[1] + bv.y;
  float v2 = xv.z + (float)ov[2] + bv.z;
  float v3 = xv.w + (float)ov[3] + bv.w;
  float s = v0 + v1 + v2 + v3;
  float ss = v0 * v0 + v1 * v1 + v2 * v2 + v3 * v3;
#pragma unroll
  for (int off = 32; off; off >>= 1) {
    s += __shfl_xor(s, off);
    ss += __shfl_xor(ss, off);
  }
  __shared__ float red[8];
  const int w = tid >> 6, lane = tid & 63;
  if (lane == 0) { red[w] = s; red[4 + w] = ss; }
  __syncthreads();
  s = red[0] + red[1] + red[2] + red[3];
  ss = red[4] + red[5] + red[6] + red[7];
  const float mu = s * (1.f / 1024.f);
  const float var = ss * (1.f / 1024.f) - mu * mu;
  const float rs = rsqrtf(var + 1e-5f);
  float4 gv = *(const float4*)(gamma + d0);
  float4 bev = *(const float4*)(beta + d0);
  float4 o;
  o.x = (v0 - mu) * rs * gv.x + bev.x;
  o.y = (v1 - mu) * rs * gv.y + bev.y;
  o.z = (v2 - mu) * rs * gv.z + bev.z;
  o.w = (v3 - mu) * rs * gv.w + bev.w;
  *(float4*)(y + rb) = o;
}

// ---------------------------------------------------------------------------
extern "C" void kernel_launch(void* const* d_in, const int* in_sizes, int n_in,
                              void* d_out, int out_size, void* d_ws, size_t ws_size,
                              hipStream_t stream) {
  const float* x     = (const float*)d_in[0];
  const float* ctxin = (const float*)d_in[1];
  const float* lut   = (const float*)d_in[2];
  const float* Wq    = (const float*)d_in[3];
  const float* Wk    = (const float*)d_in[4];
  const float* Wv    = (const float*)d_in[5];
  const float* Wo    = (const float*)d_in[6];
  const float* bo    = (const float*)d_in[7];
  const float* gam   = (const float*)d_in[8];
  const float* bet   = (const float*)d_in[9];
  float* out = (float*)d_out;

  char* ws = (char*)d_ws;
  __bf16* Xb    = (__bf16*)(ws);                        // 4 MB  [2048][1024]
  __bf16* Cb    = (__bf16*)(ws + ((size_t)4 << 20));    // 4 MB  [2048][1024]
  __bf16* Wqkvt = (__bf16*)(ws + ((size_t)8 << 20));    // 6 MB  [3072][1024]
  __bf16* Wot   = (__bf16*)(ws + ((size_t)14 << 20));   // 2 MB  [1024][1024]
  __bf16* QKVb  = (__bf16*)(ws + ((size_t)16 << 20));   // 12 MB [2048][3072]
  __bf16* CtxB  = (__bf16*)(ws + ((size_t)28 << 20));   // 4 MB  [2048][1024]
  __bf16* OutB  = (__bf16*)(ws + ((size_t)32 << 20));   // 4 MB  [2048][1024]

  // 1. weights transpose (z<4) + x/context cvt (z=4,5), one dispatch
  prep2<<<dim3(16, 16, 6), 256, 0, stream>>>(x, ctxin, Wq, Wk, Wv, Wo,
                                             Xb, Cb, Wqkvt, Wot);

  // 2. fused QKV projection, BM=64 tile: 24x32 = 768 blocks = 3/CU balanced
  gemm_bf16<64><<<dim3(24, 32), 256, 0, stream>>>(Xb, Cb, 1024, Wqkvt,
                                                  QKVb, 1024, 3072);

  // 3. band attention
  attn_band_v3<<<dim3(16, 16, 2), 256, 0, stream>>>(QKVb, lut, CtxB);

  // 4. output projection
  gemm_bf16<64><<<dim3(8, 32), 256, 0, stream>>>(CtxB, CtxB, 0, Wot,
                                                 OutB, 1024, 1024);

  // 5. residual + bias + layernorm
  ln_residual<<<2048, 256, 0, stream>>>(x, OutB, bo, gam, bet, out);
}